// Round 8
// baseline (431.188 us; speedup 1.0000x reference)
//
#include <hip/hip_runtime.h>
#include <hip/hip_bf16.h>

// Swin block on MI355X. Round 8: gemm256 K-loop restructured — stage ALL 4
// half-tiles of t+1 at tile top, vmcnt(8) (full-tile slack), pure compute
// phases. Everything else unchanged from round 7.

typedef __bf16 bf16x8 __attribute__((ext_vector_type(8)));
typedef __bf16 bf16x4 __attribute__((ext_vector_type(4)));
typedef float  f32x4  __attribute__((ext_vector_type(4)));

#define GAS __attribute__((address_space(1)))
#define LAS __attribute__((address_space(3)))

__device__ __forceinline__ void gload_lds16(const void* g, void* l) {
  __builtin_amdgcn_global_load_lds((const GAS void*)g, (LAS void*)l, 16, 0, 0);
}

__device__ __forceinline__ int div7u(int m) { return (m * 37) >> 8; }  // valid m<56

// exact GELU via A&S 7.1.26 erf (|err|<=1.5e-7), branch-free
__device__ __forceinline__ float gelu_f(float v) {
  float s = fabsf(v) * 0.70710678118f;
  float t = __builtin_amdgcn_rcpf(__builtin_fmaf(0.3275911f, s, 1.f));
  float p = t * (0.254829592f +
            t * (-0.284496736f +
            t * (1.421413741f +
            t * (-1.453152027f +
            t * 1.061405429f))));
  float erfa = __builtin_fmaf(-p, __expf(-s * s), 1.f);
  return __builtin_fmaf(0.5f * fabsf(v), erfa, 0.5f * v);
}

// ---------------- fp32 -> bf16 weight convert (one launch) ----------------
__global__ __launch_bounds__(256) void cvt_all_kernel(const float* __restrict__ s0,
                                                      const float* __restrict__ s1,
                                                      const float* __restrict__ s2,
                                                      const float* __restrict__ s3,
                                                      __bf16* __restrict__ d0,
                                                      __bf16* __restrict__ d1,
                                                      __bf16* __restrict__ d2,
                                                      __bf16* __restrict__ d3) {
  int i = blockIdx.x * 256 + threadIdx.x;
  if (i < 442368) { d0[i] = (__bf16)s0[i]; return; }
  i -= 442368;
  if (i < 147456) { d1[i] = (__bf16)s1[i]; return; }
  i -= 147456;
  if (i < 589824) { d2[i] = (__bf16)s2[i]; return; }
  i -= 589824;
  d3[i] = (__bf16)s3[i];
}

// ---------------- relative-position bias expand: [6][64][64] ----------------
__global__ __launch_bounds__(256) void bias_expand_kernel(const float* __restrict__ tbl,
                                                          float* __restrict__ be) {
  int idx = blockIdx.x * 256 + threadIdx.x;
  if (idx >= 6 * 64 * 64) return;
  int m = idx & 63, n = (idx >> 6) & 63, h = idx >> 12;
  float v = 0.f;
  if (m < 49 && n < 49) {
    int in_ = div7u(n), jn = n - in_ * 7;
    int im  = div7u(m), jm = m - im * 7;
    int t = (in_ - im + 6) * 13 + (jn - jm + 6);
    v = tbl[t * 6 + h];
  }
  be[idx] = v;
}

// ---------------- LayerNorm(channel) + transpose to token-major bf16 ----------------
__global__ __launch_bounds__(256) void ln_t_kernel(const float* __restrict__ x,
                                                   const float* __restrict__ gw,
                                                   const float* __restrict__ gb,
                                                   __bf16* __restrict__ out) {
  __shared__ f32x4 ps[16][16], ps2[16][16];        // [sub][gq]
  __shared__ __align__(16) __bf16 tile[64][198];
  const int tid = threadIdx.x;
  const int lane = tid & 63, w = tid >> 6;
  const int gq = lane & 15;
  const int sub = (w << 2) + (lane >> 4);
  const int tok0 = blockIdx.x << 6;
  const int tokg4 = tok0 + (gq << 2);
  const unsigned b = (unsigned)tokg4 / 784u;
  const unsigned p = (unsigned)tokg4 - b * 784u;
  const float* xp = x + (size_t)b * 301056u + p;

  f32x4 vals[24];
  f32x4 s4 = {0.f, 0.f, 0.f, 0.f}, s24 = {0.f, 0.f, 0.f, 0.f};
  #pragma unroll
  for (int half = 0; half < 2; ++half)
    #pragma unroll
    for (int k = 0; k < 12; ++k) {
      int c = half * 192 + sub * 12 + k;
      f32x4 v = *(const f32x4*)(xp + (size_t)c * 784u);
      vals[half * 12 + k] = v;
      s4 += v;
      s24 += v * v;
    }
  ps[sub][gq] = s4;
  ps2[sub][gq] = s24;
  __syncthreads();
  f32x4 S = {0.f, 0.f, 0.f, 0.f}, S2 = {0.f, 0.f, 0.f, 0.f};
  #pragma unroll
  for (int i = 0; i < 16; ++i) { S += ps[i][gq]; S2 += ps2[i][gq]; }
  f32x4 mean = S * (1.f / 384.f);
  f32x4 var = (S2 - S * mean) * (1.f / 383.f);
  f32x4 rstd;
  #pragma unroll
  for (int j = 0; j < 4; ++j) rstd[j] = rsqrtf(var[j] + 1e-5f);

  #pragma unroll
  for (int half = 0; half < 2; ++half) {
    if (half) __syncthreads();
    #pragma unroll
    for (int k = 0; k < 12; ++k) {
      int c = half * 192 + sub * 12 + k;
      float wgt = gw[c], bia = gb[c];
      f32x4 v = (vals[half * 12 + k] - mean) * rstd * wgt + bia;
      #pragma unroll
      for (int j = 0; j < 4; ++j)
        tile[(gq << 2) + j][sub * 12 + k] = (__bf16)v[j];
    }
    __syncthreads();
    #pragma unroll
    for (int it = 0; it < 6; ++it) {
      int idx = (it << 8) + tid;
      int row = idx / 24, colc = idx - row * 24;
      bf16x8 vv = *(const bf16x8*)(&tile[row][colc << 3]);
      *(bf16x8*)(out + (size_t)(tok0 + row) * 384 + half * 192 + (colc << 3)) = vv;
    }
  }
}

// ---------------- 256x256 8-wave pipelined GEMM (K=384 fixed) ----------------
// Stage ALL of tile t+1 at tile top -> vmcnt(8) has a full K-tile of slack.
template <int EPI>
__global__ __launch_bounds__(512, 2) void gemm256(const __bf16* __restrict__ A,
                                                  const __bf16* __restrict__ Bt, int ldb,
                                                  int My, int Mreal,
                                                  __bf16* __restrict__ outT, int ldo) {
  __shared__ __align__(16) char smem[131072];   // 2 bufs x (A 32K | B 32K)
  const int tid = threadIdx.x;
  const int lane = tid & 63;
  const int w = tid >> 6;                       // 0..7
  const int wr = w >> 2, wc = w & 3;            // 2 x 4 wave grid
  const int c = lane & 15, g = lane >> 4;

  // bijective XCD-chunk swizzle + y-fast decode
  const int nwg = gridDim.x;
  const int orig = blockIdx.x;
  const int q = nwg >> 3, r = nwg & 7;
  const int xcd = orig & 7, ii = orig >> 3;
  const int wgid = (xcd < r ? xcd * (q + 1) : r * (q + 1) + (xcd - r) * q) + ii;
  const int bx = wgid / My;
  const int by = wgid - bx * My;
  const int m0 = by << 8;
  const int n0 = bx << 8;

  // staging: wave w covers rows w*8..w*8+7 of each 64-row half; pre-swizzled src
  const int r0 = tid >> 3;
  const int kk = ((tid & 7) ^ ((tid >> 3) & 7)) << 3;
  const __bf16* pA[4];
  const __bf16* pB[4];
  #pragma unroll
  for (int j = 0; j < 4; ++j) {
    int ra = m0 + j * 64 + r0; if (ra > Mreal - 1) ra = Mreal - 1;   // pad clamp
    pA[j] = A + (size_t)ra * 384 + kk;
    pB[j] = Bt + (size_t)(n0 + j * 64 + r0) * ldb + kk;
  }
  const int dstw = w << 10;                     // (w*64)*16
  auto stage = [&](int buf, int ht, int k0) {   // ht: 0,1=A halves; 2,3=B halves
    char* d = smem + (buf << 16) + (ht << 14) + dstw;
    const __bf16* p0 = (ht < 2) ? pA[ht << 1] : pB[(ht - 2) << 1];
    const __bf16* p1 = (ht < 2) ? pA[(ht << 1) + 1] : pB[((ht - 2) << 1) + 1];
    gload_lds16(p0 + k0, d);
    gload_lds16(p1 + k0, d + 8192);
  };

  // fragment read offsets (swizzle key = c&7)
  const int off0 = (g << 4) ^ ((c & 7) << 4);
  const int off1 = off0 ^ 64;
  const int aB = (wr << 14) + (c << 7);
  const int bB = 32768 + (wc << 13) + (c << 7);

  f32x4 acc[8][4];
  #pragma unroll
  for (int i = 0; i < 8; ++i)
    #pragma unroll
    for (int j = 0; j < 4; ++j) acc[i][j] = (f32x4){0.f, 0.f, 0.f, 0.f};

  stage(0, 0, 0); stage(0, 1, 0); stage(0, 2, 0); stage(0, 3, 0);

  bf16x8 aX[4], aY[4], b0[4], b1[4];
  #pragma unroll
  for (int t = 0; t < 6; ++t) {
    const int cur = t & 1, nxt = cur ^ 1;
    const int k1 = (t + 1) << 6;
    const char* sc = smem + (cur << 16);
    // ---- tile top: stage ALL of t+1, wait only on t's 8 (full-tile slack) ----
    if (t < 5) {
      stage(nxt, 0, k1); stage(nxt, 1, k1); stage(nxt, 2, k1); stage(nxt, 3, k1);
      asm volatile("s_waitcnt vmcnt(8)" ::: "memory");
    } else {
      asm volatile("s_waitcnt vmcnt(0)" ::: "memory");
    }
    __builtin_amdgcn_s_barrier();               // union: all waves' t-loads landed
    // ---- phase 1: (mi 0-3, ks0) ----
    #pragma unroll
    for (int mi = 0; mi < 4; ++mi) aX[mi] = *(const bf16x8*)(sc + aB + mi * 2048 + off0);
    #pragma unroll
    for (int nj = 0; nj < 4; ++nj) b0[nj] = *(const bf16x8*)(sc + bB + nj * 2048 + off0);
    asm volatile("s_waitcnt lgkmcnt(0)" ::: "memory");
    __builtin_amdgcn_sched_barrier(0);
    __builtin_amdgcn_s_setprio(1);
    #pragma unroll
    for (int mi = 0; mi < 4; ++mi)
      #pragma unroll
      for (int nj = 0; nj < 4; ++nj)
        acc[mi][nj] = __builtin_amdgcn_mfma_f32_16x16x32_bf16(aX[mi], b0[nj], acc[mi][nj], 0, 0, 0);
    __builtin_amdgcn_s_setprio(0);
    // ---- phase 2: (mi 4-7, ks0) ----
    #pragma unroll
    for (int mi = 0; mi < 4; ++mi) aY[mi] = *(const bf16x8*)(sc + aB + (4 + mi) * 2048 + off0);
    asm volatile("s_waitcnt lgkmcnt(0)" ::: "memory");
    __builtin_amdgcn_sched_barrier(0);
    __builtin_amdgcn_s_setprio(1);
    #pragma unroll
    for (int mi = 0; mi < 4; ++mi)
      #pragma unroll
      for (int nj = 0; nj < 4; ++nj)
        acc[4 + mi][nj] = __builtin_amdgcn_mfma_f32_16x16x32_bf16(aY[mi], b0[nj], acc[4 + mi][nj], 0, 0, 0);
    __builtin_amdgcn_s_setprio(0);
    // ---- phase 3: (mi 0-3, ks1) ----
    #pragma unroll
    for (int mi = 0; mi < 4; ++mi) aX[mi] = *(const bf16x8*)(sc + aB + mi * 2048 + off1);
    #pragma unroll
    for (int nj = 0; nj < 4; ++nj) b1[nj] = *(const bf16x8*)(sc + bB + nj * 2048 + off1);
    asm volatile("s_waitcnt lgkmcnt(0)" ::: "memory");
    __builtin_amdgcn_sched_barrier(0);
    __builtin_amdgcn_s_setprio(1);
    #pragma unroll
    for (int mi = 0; mi < 4; ++mi)
      #pragma unroll
      for (int nj = 0; nj < 4; ++nj)
        acc[mi][nj] = __builtin_amdgcn_mfma_f32_16x16x32_bf16(aX[mi], b1[nj], acc[mi][nj], 0, 0, 0);
    __builtin_amdgcn_s_setprio(0);
    // ---- phase 4: (mi 4-7, ks1) ----
    #pragma unroll
    for (int mi = 0; mi < 4; ++mi) aY[mi] = *(const bf16x8*)(sc + aB + (4 + mi) * 2048 + off1);
    asm volatile("s_waitcnt lgkmcnt(0)" ::: "memory");
    __builtin_amdgcn_sched_barrier(0);
    __builtin_amdgcn_s_setprio(1);
    #pragma unroll
    for (int mi = 0; mi < 4; ++mi)
      #pragma unroll
      for (int nj = 0; nj < 4; ++nj)
        acc[4 + mi][nj] = __builtin_amdgcn_mfma_f32_16x16x32_bf16(aY[mi], b1[nj], acc[4 + mi][nj], 0, 0, 0);
    __builtin_amdgcn_s_setprio(0);
    __builtin_amdgcn_s_barrier();               // all reads of buf cur done
  }

  // ---- epilogue: per-wave [64 tok][128 m] swizzled LDS transpose -> global ----
  __syncthreads();
  char* tw = smem + (w << 14);
  #pragma unroll
  for (int mi = 0; mi < 8; ++mi)
    #pragma unroll
    for (int nj = 0; nj < 4; ++nj) {
      f32x4 v = acc[mi][nj];
      if constexpr (EPI == 1) {
        #pragma unroll
        for (int j = 0; j < 4; ++j) v[j] = gelu_f(v[j]);
      }
      bf16x4 pk = {(__bf16)v[0], (__bf16)v[1], (__bf16)v[2], (__bf16)v[3]};
      int tok = (nj << 4) + c;
      int mb = (mi << 5) + (g << 3);
      *(bf16x4*)(tw + (tok << 8) + (mb ^ ((tok & 7) << 4))) = pk;
    }
  __syncthreads();
  const int tokl = lane >> 4;
  const int ch = lane & 15;
  const int mg = m0 + (wr << 7) + (ch << 3);
  if (mg < Mreal) {
    #pragma unroll
    for (int rep = 0; rep < 16; ++rep) {
      int tok = (rep << 2) + tokl;
      bf16x8 v = *(const bf16x8*)(tw + (tok << 8) + ((ch << 4) ^ ((tok & 7) << 4)));
      *(bf16x8*)(outT + (size_t)(n0 + (wc << 6) + tok) * ldo + mg) = v;
    }
  }
}

// ---------------- 128x128 GEMM (EPI2: resid+store fp32 channel-major) ----------------
template <int EPI>
__global__ __launch_bounds__(256, 2) void gemm_bt(const __bf16* __restrict__ A, int lda,
                                                  const __bf16* __restrict__ Bt, int ldb,
                                                  int K, int My,
                                                  float* __restrict__ outR,
                                                  const float* __restrict__ resid,
                                                  int tok_off) {
  __shared__ __align__(16) char smem[65536];
  const int tid = threadIdx.x;
  const int lane = tid & 63;
  const int w = tid >> 6;
  const int wr = w >> 1, wc = w & 1;
  const int c = lane & 15, g = lane >> 4;

  const int nwg = gridDim.x;
  const int orig = blockIdx.x;
  const int q = nwg >> 3, r = nwg & 7;
  const int xcd = orig & 7, ii = orig >> 3;
  const int base = xcd < r ? xcd * (q + 1) : r * (q + 1) + (xcd - r) * q;
  const int wgid = base + ii;
  const int bx = wgid / My;
  const int by = wgid - bx * My;
  const int m0 = by << 7;
  const int n0 = bx << 7;

  const __bf16* ap[4];
  const __bf16* bp[4];
  #pragma unroll
  for (int i = 0; i < 4; ++i) {
    int s = (i << 8) + tid;
    int row = s >> 3;
    int kkk = ((s ^ row) & 7) << 3;
    ap[i] = A  + (size_t)(m0 + row) * lda + kkk;
    bp[i] = Bt + (size_t)(n0 + row) * ldb + kkk;
  }
  auto stage = [&](int buf, int k0) {
    #pragma unroll
    for (int i = 0; i < 4; ++i) {
      gload_lds16(ap[i] + k0, smem + (buf << 15) + (((i << 8) + (w << 6)) << 4));
      gload_lds16(bp[i] + k0, smem + (buf << 15) + 16384 + (((i << 8) + (w << 6)) << 4));
    }
  };

  f32x4 acc[4][4] = {};
  const int nt = K >> 6;
  stage(0, 0);
  int cur = 0;
  for (int t = 0; t < nt; ++t) {
    if (t + 1 < nt) {
      stage(cur ^ 1, (t + 1) << 6);
      asm volatile("s_waitcnt vmcnt(8)" ::: "memory");
    } else {
      asm volatile("s_waitcnt vmcnt(0)" ::: "memory");
    }
    __builtin_amdgcn_s_barrier();
    __builtin_amdgcn_sched_barrier(0);
    const char* smA = smem + (cur << 15);
    const char* smB = smA + 16384;
    #pragma unroll
    for (int ks = 0; ks < 2; ++ks) {
      bf16x8 af[4], bfv[4];
      #pragma unroll
      for (int mi = 0; mi < 4; ++mi) {
        int r2 = (wr << 6) + (mi << 4) + c;
        af[mi] = *(const bf16x8*)(smA + (r2 << 7) + (((ks << 6) + (g << 4)) ^ ((r2 & 7) << 4)));
      }
      #pragma unroll
      for (int nj = 0; nj < 4; ++nj) {
        int r2 = (wc << 6) + (nj << 4) + c;
        bfv[nj] = *(const bf16x8*)(smB + (r2 << 7) + (((ks << 6) + (g << 4)) ^ ((r2 & 7) << 4)));
      }
      #pragma unroll
      for (int mi = 0; mi < 4; ++mi)
        #pragma unroll
        for (int nj = 0; nj < 4; ++nj)
          acc[mi][nj] = __builtin_amdgcn_mfma_f32_16x16x32_bf16(bfv[nj], af[mi], acc[mi][nj], 0, 0, 0);
    }
    __builtin_amdgcn_s_barrier();
    cur ^= 1;
  }

  #pragma unroll
  for (int nj = 0; nj < 4; ++nj) {
    int tokb = tok_off + n0 + (wc << 6) + (nj << 4) + (g << 2);
    unsigned bb = (unsigned)tokb / 784u;
    unsigned pp = (unsigned)tokb - bb * 784u;
    size_t base2 = (size_t)bb * (384u * 784u) + pp;
    #pragma unroll
    for (int mi = 0; mi < 4; ++mi) {
      int o = m0 + (wr << 6) + (mi << 4) + c;
      size_t a2 = base2 + (size_t)o * 784u;
      f32x4 rv = *(const f32x4*)(resid + a2);
      f32x4 v = acc[mi][nj] + rv;
      *(f32x4*)(outR + a2) = v;
    }
  }
}

// ---------------- windowed attention: 1 wave per (window, head) ----------------
__global__ __launch_bounds__(256, 2) void attn_kernel(const __bf16* __restrict__ qkv,
                                                      const float* __restrict__ be,
                                                      __bf16* __restrict__ outt) {
  __shared__ __align__(16) char smem_all[4][16384];
  const int tid = threadIdx.x;
  const int lane = tid & 63;
  const int w = tid >> 6;
  char* sm = (char*)smem_all[w];
  const int pair = blockIdx.x * 4 + w;               // 6144 pairs
  const int h = pair % 6;
  const int wg = pair / 6;
  const int b = wg >> 4;
  const int wi = wg & 15;
  const int wh = wi >> 2, wwi = wi & 3;
  const int cc = lane & 15, g = lane >> 4;

  {
    int rsub = lane >> 3;
    int slot = lane & 7;
    int dc = (slot ^ rsub) << 3;
    #pragma unroll
    for (int i = 0; i < 8; ++i) {
      int r = i * 8 + rsub;
      int m = r < 49 ? r : 48;
      int im = div7u(m), jm = m - im * 7;
      int sh = wh * 7 + im + 3; if (sh >= 28) sh -= 28;
      int sw = wwi * 7 + jm + 3; if (sw >= 28) sw -= 28;
      size_t trow = (size_t)(b * 784 + sh * 28 + sw) * 1152;
      gload_lds16(qkv + trow + 384 + h * 64 + dc, sm + i * 1024);         // K
      gload_lds16(qkv + trow +       h * 64 + dc, sm + 8192 + i * 1024);  // Q
    }
  }
  asm volatile("s_waitcnt vmcnt(0)" ::: "memory");
  __syncthreads();

  f32x4 sacc[4][4] = {};
  #pragma unroll
  for (int ks = 0; ks < 2; ++ks) {
    bf16x8 kf[4], qf[4];
    #pragma unroll
    for (int mi = 0; mi < 4; ++mi) {
      int r = (mi << 4) + cc;
      kf[mi] = *(const bf16x8*)(sm + (r << 7) + (((ks << 6) + (g << 4)) ^ ((r & 7) << 4)));
    }
    #pragma unroll
    for (int nj = 0; nj < 4; ++nj) {
      int r = (nj << 4) + cc;
      qf[nj] = *(const bf16x8*)(sm + 8192 + (r << 7) + (((ks << 6) + (g << 4)) ^ ((r & 7) << 4)));
    }
    #pragma unroll
    for (int mi = 0; mi < 4; ++mi)
      #pragma unroll
      for (int nj = 0; nj < 4; ++nj)
        sacc[mi][nj] = __builtin_amdgcn_mfma_f32_16x16x32_bf16(kf[mi], qf[nj], sacc[mi][nj], 0, 0, 0);
  }
  __syncthreads();

  int r9m[4][4];
  #pragma unroll
  for (int mi = 0; mi < 4; ++mi)
    #pragma unroll
    for (int rr = 0; rr < 4; ++rr) {
      int m = (mi << 4) + (g << 2) + rr; if (m > 48) m = 48;
      int im = div7u(m), jm = m - im * 7;
      int sh = wh * 7 + im, sw = wwi * 7 + jm;
      r9m[mi][rr] = ((sh < 21) ? 0 : (sh < 25 ? 1 : 2)) * 3 + ((sw < 21) ? 0 : (sw < 25 ? 1 : 2));
    }

  #pragma unroll
  for (int nj = 0; nj < 4; ++nj) {
    int n = (nj << 4) + cc;
    int ncl = n > 48 ? 48 : n;
    int in_ = div7u(ncl), jn = ncl - in_ * 7;
    int shn = wh * 7 + in_, swn = wwi * 7 + jn;
    int r9n = ((shn < 21) ? 0 : (shn < 25 ? 1 : 2)) * 3 + ((swn < 21) ? 0 : (swn < 25 ? 1 : 2));
    float mx = -1e30f;
    #pragma unroll
    for (int mi = 0; mi < 4; ++mi) {
      f32x4 bia = *(const f32x4*)(be + (((h << 6) + n) << 6) + (mi << 4) + (g << 2));
      #pragma unroll
      for (int rr = 0; rr < 4; ++rr) {
        int m = (mi << 4) + (g << 2) + rr;
        float t = (m < 49)
            ? sacc[mi][nj][rr] * 0.125f + bia[rr] + ((r9m[mi][rr] == r9n) ? 0.f : -100.f)
            : -1e30f;
        sacc[mi][nj][rr] = t;
        mx = fmaxf(mx, t);
      }
    }
    mx = fmaxf(mx, __shfl_xor(mx, 16, 64));
    mx = fmaxf(mx, __shfl_xor(mx, 32, 64));
    float sum = 0.f;
    #pragma unroll
    for (int mi = 0; mi < 4; ++mi)
      #pragma unroll
      for (int rr = 0; rr < 4; ++rr) {
        float e = __expf(sacc[mi][nj][rr] - mx);
        sacc[mi][nj][rr] = e;
        sum += e;
      }
    sum += __shfl_xor(sum, 16, 64);
    sum += __shfl_xor(sum, 32, 64);
    float inv = __builtin_amdgcn_rcpf(sum);
    #pragma unroll
    for (int mi = 0; mi < 4; ++mi) {
      bf16x4 pk = {(__bf16)(sacc[mi][nj][0] * inv), (__bf16)(sacc[mi][nj][1] * inv),
                   (__bf16)(sacc[mi][nj][2] * inv), (__bf16)(sacc[mi][nj][3] * inv)};
      *(bf16x4*)(sm + 8192 + (n << 7) + (((mi << 5) + (g << 3)) ^ ((n & 7) << 4))) = pk;
    }
  }

  {
    int ml = lane & 15, dq = lane >> 4;
    #pragma unroll
    for (int it = 0; it < 4; ++it) {
      int m = (it << 4) + ml;
      int mc_ = m > 48 ? 48 : m;
      int im = div7u(mc_), jm = mc_ - im * 7;
      int sh = wh * 7 + im + 3; if (sh >= 28) sh -= 28;
      int sw = wwi * 7 + jm + 3; if (sw >= 28) sw -= 28;
      const __bf16* gv = qkv + (size_t)(b * 784 + sh * 28 + sw) * 1152 + 768 + h * 64;
      #pragma unroll
      for (int hd = 0; hd < 2; ++hd) {
        int dbase = (hd << 5) + (dq << 3);
        bf16x8 v = *(const bf16x8*)(gv + dbase);
        #pragma unroll
        for (int j = 0; j < 8; ++j) {
          int d = dbase + j;
          *(__bf16*)(sm + (d << 7) + ((((m >> 3) ^ (d & 7)) << 4) + ((m & 7) << 1))) = v[j];
        }
      }
    }
  }
  __syncthreads();

  f32x4 oacc[4][4] = {};
  #pragma unroll
  for (int ks = 0; ks < 2; ++ks) {
    bf16x8 pf[4], vf[4];
    #pragma unroll
    for (int ni = 0; ni < 4; ++ni) {
      int n = (ni << 4) + cc;
      pf[ni] = *(const bf16x8*)(sm + 8192 + (n << 7) + (((ks << 6) + (g << 4)) ^ ((n & 7) << 4)));
    }
    #pragma unroll
    for (int dj = 0; dj < 4; ++dj) {
      int d = (dj << 4) + cc;
      vf[dj] = *(const bf16x8*)(sm + (d << 7) + ((((ks << 2) + g) ^ (d & 7)) << 4));
    }
    #pragma unroll
    for (int ni = 0; ni < 4; ++ni)
      #pragma unroll
      for (int dj = 0; dj < 4; ++dj)
        oacc[ni][dj] = __builtin_amdgcn_mfma_f32_16x16x32_bf16(pf[ni], vf[dj], oacc[ni][dj], 0, 0, 0);
  }

  #pragma unroll
  for (int ni = 0; ni < 4; ++ni)
    #pragma unroll
    for (int rr = 0; rr < 4; ++rr) {
      int n = (ni << 4) + (g << 2) + rr;
      if (n < 49) {
        int im = div7u(n), jn = n - im * 7;
        int sh = wh * 7 + im + 3; if (sh >= 28) sh -= 28;
        int sw = wwi * 7 + jn + 3; if (sw >= 28) sw -= 28;
        __bf16* op = outt + (size_t)(b * 784 + sh * 28 + sw) * 384 + h * 64;
        #pragma unroll
        for (int dj = 0; dj < 4; ++dj)
          op[(dj << 4) + cc] = (__bf16)oacc[ni][dj][rr];
      }
    }
}

// ---------------- host launcher ----------------
extern "C" void kernel_launch(void* const* d_in, const int* in_sizes, int n_in,
                              void* d_out, int out_size, void* d_ws, size_t ws_size,
                              hipStream_t stream) {
  (void)in_sizes; (void)n_in; (void)out_size; (void)ws_size;
  const float* x     = (const float*)d_in[0];
  const float* n1w   = (const float*)d_in[1];
  const float* n1b   = (const float*)d_in[2];
  const float* qkvw  = (const float*)d_in[3];
  const float* tbl   = (const float*)d_in[4];
  const float* projw = (const float*)d_in[5];
  const float* n2w   = (const float*)d_in[6];
  const float* n2b   = (const float*)d_in[7];
  const float* w1    = (const float*)d_in[8];
  const float* w3    = (const float*)d_in[9];
  float* out = (float*)d_out;

  char* ws = (char*)d_ws;
  __bf16* bufA = (__bf16*)ws;                               // 38,535,168 B
  __bf16* bufB = (__bf16*)(ws + 38535168);                  // 115,605,504 B
  float*  be   = (float*)(ws + 154140672);                  // 98,304 B
  __bf16* wq   = (__bf16*)(ws + 154238976);
  __bf16* wp   = wq + 442368;
  __bf16* wm1  = wp + 147456;
  __bf16* wm3  = wm1 + 589824;

  cvt_all_kernel<<<6912, 256, 0, stream>>>(qkvw, projw, w1, w3, wq, wp, wm1, wm3);
  bias_expand_kernel<<<96, 256, 0, stream>>>(tbl, be);

  // LN1 -> xn_t (bufA)
  ln_t_kernel<<<784, 256, 0, stream>>>(x, n1w, n1b, bufA);
  // qkv (256^2 pipeline; M padded 1152->1280 via row clamp) -> qkv_t (bufB)
  gemm256<0><<<196 * 5, 512, 0, stream>>>(wq, bufA, 384, 5, 1152, bufB, 1152);
  // attention -> attn_out_t (bufA)
  attn_kernel<<<1536, 256, 0, stream>>>(bufB, be, bufA);
  // proj + residual(x) -> d_out (fp32 channel-major)
  gemm_bt<2><<<392 * 3, 256, 0, stream>>>(wp, 384, bufA, 384, 384, 3, out, x, 0);
  // LN2 -> xn2_t (bufA)
  ln_t_kernel<<<784, 256, 0, stream>>>(out, n2w, n2b, bufA);
  // MLP, token-split halves: mlp1 on 256^2 pipeline + GELU, mlp2 on 128^2 EPI2
  for (int hh = 0; hh < 2; ++hh) {
    const int toff = hh * 25088;
    gemm256<1><<<98 * 6, 512, 0, stream>>>(wm1, bufA + (size_t)toff * 384, 384, 6, 1536,
                                           bufB, 1536);
    gemm_bt<2><<<196 * 3, 256, 0, stream>>>(wm3, 1536, bufB, 1536, 1536, 3,
                                            out, out, toff);
  }
}

// Round 9
// 401.149 us; speedup vs baseline: 1.0749x; 1.0749x over previous
//
#include <hip/hip_runtime.h>
#include <hip/hip_bf16.h>

// Swin block on MI355X. Round 9: revert to round-6 all-128^2 pipeline; gemm_bt
// switched to single-LDS-buffer + register-staged prefetch -> 3 blocks/CU
// (was 2 with 64KB dbuf). LN/attn/launches identical to round 6.

typedef __bf16 bf16x8 __attribute__((ext_vector_type(8)));
typedef __bf16 bf16x4 __attribute__((ext_vector_type(4)));
typedef float  f32x4  __attribute__((ext_vector_type(4)));
typedef int    i32x4  __attribute__((ext_vector_type(4)));

#define GAS __attribute__((address_space(1)))
#define LAS __attribute__((address_space(3)))

__device__ __forceinline__ int div7u(int m) { return (m * 37) >> 8; }  // valid m<56

// exact GELU via A&S 7.1.26 erf (|err|<=1.5e-7), branch-free
__device__ __forceinline__ float gelu_f(float v) {
  float s = fabsf(v) * 0.70710678118f;
  float t = __builtin_amdgcn_rcpf(__builtin_fmaf(0.3275911f, s, 1.f));
  float p = t * (0.254829592f +
            t * (-0.284496736f +
            t * (1.421413741f +
            t * (-1.453152027f +
            t * 1.061405429f))));
  float erfa = __builtin_fmaf(-p, __expf(-s * s), 1.f);
  return __builtin_fmaf(0.5f * fabsf(v), erfa, 0.5f * v);
}

// ---------------- fp32 -> bf16 weight convert (one launch) ----------------
__global__ __launch_bounds__(256) void cvt_all_kernel(const float* __restrict__ s0,
                                                      const float* __restrict__ s1,
                                                      const float* __restrict__ s2,
                                                      const float* __restrict__ s3,
                                                      __bf16* __restrict__ d0,
                                                      __bf16* __restrict__ d1,
                                                      __bf16* __restrict__ d2,
                                                      __bf16* __restrict__ d3) {
  int i = blockIdx.x * 256 + threadIdx.x;
  if (i < 442368) { d0[i] = (__bf16)s0[i]; return; }
  i -= 442368;
  if (i < 147456) { d1[i] = (__bf16)s1[i]; return; }
  i -= 147456;
  if (i < 589824) { d2[i] = (__bf16)s2[i]; return; }
  i -= 589824;
  d3[i] = (__bf16)s3[i];
}

// ---------------- relative-position bias expand: [6][64][64] ----------------
__global__ __launch_bounds__(256) void bias_expand_kernel(const float* __restrict__ tbl,
                                                          float* __restrict__ be) {
  int idx = blockIdx.x * 256 + threadIdx.x;
  if (idx >= 6 * 64 * 64) return;
  int m = idx & 63, n = (idx >> 6) & 63, h = idx >> 12;
  float v = 0.f;
  if (m < 49 && n < 49) {
    int in_ = div7u(n), jn = n - in_ * 7;
    int im  = div7u(m), jm = m - im * 7;
    int t = (in_ - im + 6) * 13 + (jn - jm + 6);
    v = tbl[t * 6 + h];
  }
  be[idx] = v;
}

// ---------------- LayerNorm(channel) + transpose to token-major bf16 ----------------
__global__ __launch_bounds__(256) void ln_t_kernel(const float* __restrict__ x,
                                                   const float* __restrict__ gw,
                                                   const float* __restrict__ gb,
                                                   __bf16* __restrict__ out) {
  __shared__ f32x4 ps[16][16], ps2[16][16];        // [sub][gq]
  __shared__ __align__(16) __bf16 tile[64][198];
  const int tid = threadIdx.x;
  const int lane = tid & 63, w = tid >> 6;
  const int gq = lane & 15;
  const int sub = (w << 2) + (lane >> 4);
  const int tok0 = blockIdx.x << 6;
  const int tokg4 = tok0 + (gq << 2);
  const unsigned b = (unsigned)tokg4 / 784u;
  const unsigned p = (unsigned)tokg4 - b * 784u;
  const float* xp = x + (size_t)b * 301056u + p;

  f32x4 vals[24];
  f32x4 s4 = {0.f, 0.f, 0.f, 0.f}, s24 = {0.f, 0.f, 0.f, 0.f};
  #pragma unroll
  for (int half = 0; half < 2; ++half)
    #pragma unroll
    for (int k = 0; k < 12; ++k) {
      int c = half * 192 + sub * 12 + k;
      f32x4 v = *(const f32x4*)(xp + (size_t)c * 784u);
      vals[half * 12 + k] = v;
      s4 += v;
      s24 += v * v;
    }
  ps[sub][gq] = s4;
  ps2[sub][gq] = s24;
  __syncthreads();
  f32x4 S = {0.f, 0.f, 0.f, 0.f}, S2 = {0.f, 0.f, 0.f, 0.f};
  #pragma unroll
  for (int i = 0; i < 16; ++i) { S += ps[i][gq]; S2 += ps2[i][gq]; }
  f32x4 mean = S * (1.f / 384.f);
  f32x4 var = (S2 - S * mean) * (1.f / 383.f);     // unbiased (ddof=1)
  f32x4 rstd;
  #pragma unroll
  for (int j = 0; j < 4; ++j) rstd[j] = rsqrtf(var[j] + 1e-5f);

  #pragma unroll
  for (int half = 0; half < 2; ++half) {
    if (half) __syncthreads();
    #pragma unroll
    for (int k = 0; k < 12; ++k) {
      int c = half * 192 + sub * 12 + k;
      float wgt = gw[c], bia = gb[c];
      f32x4 v = (vals[half * 12 + k] - mean) * rstd * wgt + bia;
      #pragma unroll
      for (int j = 0; j < 4; ++j)
        tile[(gq << 2) + j][sub * 12 + k] = (__bf16)v[j];
    }
    __syncthreads();
    #pragma unroll
    for (int it = 0; it < 6; ++it) {
      int idx = (it << 8) + tid;
      int row = idx / 24, colc = idx - row * 24;
      bf16x8 vv = *(const bf16x8*)(&tile[row][colc << 3]);
      *(bf16x8*)(out + (size_t)(tok0 + row) * 384 + half * 192 + (colc << 3)) = vv;
    }
  }
}

// ---------------- GEMM: C[m][tok] = sum_k A[m][k] * Bt[tok][k] ----------------
// 128x128 tile, BK=64, SINGLE LDS buffer (33.8KB -> 3 blocks/CU), reg-staged
// prefetch (T14): load t+1 -> 32 VGPR during compute of t; barrier; ds_write;
// barrier. Bijective XCD-chunk swizzle + y-fast decode.
// EPI 0: LDS-transpose -> bf16 outT[tok][ldo] @ ocol
// EPI 1: same + exact GELU (polynomial)
// EPI 2: swapped-operand acc -> float4 resid+store fp32 channel-major
template <int EPI>
__global__ __launch_bounds__(256, 3) void gemm_bt(const __bf16* __restrict__ A, int lda,
                                                  const __bf16* __restrict__ Bt, int ldb,
                                                  int K, int My,
                                                  __bf16* __restrict__ outT, int ldo, int ocol,
                                                  float* __restrict__ outR,
                                                  const float* __restrict__ resid,
                                                  int tok_off) {
  __shared__ __align__(16) char smem[33792];   // K-tile buf 32KB; epi transpose 33KB
  const int tid = threadIdx.x;
  const int lane = tid & 63;
  const int w = tid >> 6;
  const int wr = w >> 1, wc = w & 1;
  const int c = lane & 15, g = lane >> 4;

  const int nwg = gridDim.x;
  const int orig = blockIdx.x;
  const int q = nwg >> 3, r = nwg & 7;
  const int xcd = orig & 7, ii = orig >> 3;
  const int wgid = (xcd < r ? xcd * (q + 1) : r * (q + 1) + (xcd - r) * q) + ii;
  const int bx = wgid / My;
  const int by = wgid - bx * My;
  const int m0 = by << 7;
  const int n0 = bx << 7;

  // staging addresses: slot s=i*256+tid -> row s>>3, pre-swizzled k-chunk
  const __bf16* ap[4];
  const __bf16* bp[4];
  #pragma unroll
  for (int i = 0; i < 4; ++i) {
    int s = (i << 8) + tid;
    int row = s >> 3;
    int kk = ((s ^ row) & 7) << 3;
    ap[i] = A  + (size_t)(m0 + row) * lda + kk;
    bp[i] = Bt + (size_t)(n0 + row) * ldb + kk;
  }

  i32x4 sA0, sA1, sA2, sA3, sB0, sB1, sB2, sB3;  // staged regs (static names)
  auto issue = [&](int k0) {
    sA0 = *(const i32x4*)(ap[0] + k0); sB0 = *(const i32x4*)(bp[0] + k0);
    sA1 = *(const i32x4*)(ap[1] + k0); sB1 = *(const i32x4*)(bp[1] + k0);
    sA2 = *(const i32x4*)(ap[2] + k0); sB2 = *(const i32x4*)(bp[2] + k0);
    sA3 = *(const i32x4*)(ap[3] + k0); sB3 = *(const i32x4*)(bp[3] + k0);
  };
  auto write_lds = [&]() {
    *(i32x4*)(smem +         (((0 << 8) + tid) << 4)) = sA0;
    *(i32x4*)(smem +         (((1 << 8) + tid) << 4)) = sA1;
    *(i32x4*)(smem +         (((2 << 8) + tid) << 4)) = sA2;
    *(i32x4*)(smem +         (((3 << 8) + tid) << 4)) = sA3;
    *(i32x4*)(smem + 16384 + (((0 << 8) + tid) << 4)) = sB0;
    *(i32x4*)(smem + 16384 + (((1 << 8) + tid) << 4)) = sB1;
    *(i32x4*)(smem + 16384 + (((2 << 8) + tid) << 4)) = sB2;
    *(i32x4*)(smem + 16384 + (((3 << 8) + tid) << 4)) = sB3;
  };

  f32x4 acc[4][4] = {};
  const int nt = K >> 6;

  issue(0);
  write_lds();                                       // compiler inserts vmcnt deps
  asm volatile("s_waitcnt lgkmcnt(0)" ::: "memory");
  __builtin_amdgcn_s_barrier();
  __builtin_amdgcn_sched_barrier(0);

  for (int t = 0; t < nt; ++t) {
    if (t + 1 < nt) issue((t + 1) << 6);             // in flight across compute
    const char* smA = smem;
    const char* smB = smem + 16384;
    #pragma unroll
    for (int ks = 0; ks < 2; ++ks) {
      bf16x8 af[4], bfv[4];
      #pragma unroll
      for (int mi = 0; mi < 4; ++mi) {
        int r2 = (wr << 6) + (mi << 4) + c;
        af[mi] = *(const bf16x8*)(smA + (r2 << 7) + (((ks << 6) + (g << 4)) ^ ((r2 & 7) << 4)));
      }
      #pragma unroll
      for (int nj = 0; nj < 4; ++nj) {
        int r2 = (wc << 6) + (nj << 4) + c;
        bfv[nj] = *(const bf16x8*)(smB + (r2 << 7) + (((ks << 6) + (g << 4)) ^ ((r2 & 7) << 4)));
      }
      #pragma unroll
      for (int mi = 0; mi < 4; ++mi)
        #pragma unroll
        for (int nj = 0; nj < 4; ++nj) {
          if constexpr (EPI == 2)  // swapped: C rows = tokens
            acc[mi][nj] = __builtin_amdgcn_mfma_f32_16x16x32_bf16(bfv[nj], af[mi], acc[mi][nj], 0, 0, 0);
          else
            acc[mi][nj] = __builtin_amdgcn_mfma_f32_16x16x32_bf16(af[mi], bfv[nj], acc[mi][nj], 0, 0, 0);
        }
    }
    __builtin_amdgcn_s_barrier();                    // all waves done reading buf
    if (t + 1 < nt) {
      write_lds();                                   // vmcnt deps auto-inserted
      asm volatile("s_waitcnt lgkmcnt(0)" ::: "memory");
    }
    __builtin_amdgcn_s_barrier();                    // writes visible to all
    __builtin_amdgcn_sched_barrier(0);               // no read hoisting above
  }

  if constexpr (EPI <= 1) {
    #pragma unroll
    for (int mi = 0; mi < 4; ++mi)
      #pragma unroll
      for (int nj = 0; nj < 4; ++nj) {
        f32x4 v = acc[mi][nj];
        if constexpr (EPI == 1) {
          #pragma unroll
          for (int r2 = 0; r2 < 4; ++r2) v[r2] = gelu_f(v[r2]);
        }
        bf16x4 pk = {(__bf16)v[0], (__bf16)v[1], (__bf16)v[2], (__bf16)v[3]};
        int nl = (wc << 6) + (nj << 4) + c;
        int ml = (wr << 6) + (mi << 4) + (g << 2);
        *(bf16x4*)(smem + nl * 264 + ml * 2) = pk;
      }
    __syncthreads();
    #pragma unroll
    for (int it = 0; it < 8; ++it) {
      int id = (it << 8) + tid;
      int n = id >> 4, mc = id & 15;
      bf16x8 v = *(const bf16x8*)(smem + n * 264 + (mc << 4));
      *(bf16x8*)(outT + (size_t)(n0 + n) * ldo + (ocol + m0 + (mc << 3))) = v;
    }
  } else {
    #pragma unroll
    for (int nj = 0; nj < 4; ++nj) {
      int tokb = tok_off + n0 + (wc << 6) + (nj << 4) + (g << 2);
      unsigned bb = (unsigned)tokb / 784u;
      unsigned pp = (unsigned)tokb - bb * 784u;
      size_t base2 = (size_t)bb * (384u * 784u) + pp;
      #pragma unroll
      for (int mi = 0; mi < 4; ++mi) {
        int o = m0 + (wr << 6) + (mi << 4) + c;
        size_t a2 = base2 + (size_t)o * 784u;
        f32x4 rv = *(const f32x4*)(resid + a2);
        f32x4 v = acc[mi][nj] + rv;
        *(f32x4*)(outR + a2) = v;
      }
    }
  }
}

// ---------------- windowed attention: 1 wave per (window, head) ----------------
__global__ __launch_bounds__(256, 2) void attn_kernel(const __bf16* __restrict__ qkv,
                                                      const float* __restrict__ be,
                                                      __bf16* __restrict__ outt) {
  __shared__ __align__(16) char smem_all[4][16384];
  const int tid = threadIdx.x;
  const int lane = tid & 63;
  const int w = tid >> 6;
  char* sm = (char*)smem_all[w];
  const int pair = blockIdx.x * 4 + w;               // 6144 pairs
  const int h = pair % 6;
  const int wg = pair / 6;
  const int b = wg >> 4;
  const int wi = wg & 15;
  const int wh = wi >> 2, wwi = wi & 3;
  const int cc = lane & 15, g = lane >> 4;

  {
    int rsub = lane >> 3;
    int slot = lane & 7;
    int dc = (slot ^ rsub) << 3;
    #pragma unroll
    for (int i = 0; i < 8; ++i) {
      int r = i * 8 + rsub;
      int m = r < 49 ? r : 48;
      int im = div7u(m), jm = m - im * 7;
      int sh = wh * 7 + im + 3; if (sh >= 28) sh -= 28;
      int sw = wwi * 7 + jm + 3; if (sw >= 28) sw -= 28;
      size_t trow = (size_t)(b * 784 + sh * 28 + sw) * 1152;
      __builtin_amdgcn_global_load_lds((const GAS void*)(qkv + trow + 384 + h * 64 + dc),
                                       (LAS void*)(sm + i * 1024), 16, 0, 0);
      __builtin_amdgcn_global_load_lds((const GAS void*)(qkv + trow + h * 64 + dc),
                                       (LAS void*)(sm + 8192 + i * 1024), 16, 0, 0);
    }
  }
  asm volatile("s_waitcnt vmcnt(0)" ::: "memory");
  __syncthreads();

  f32x4 sacc[4][4] = {};
  #pragma unroll
  for (int ks = 0; ks < 2; ++ks) {
    bf16x8 kf[4], qf[4];
    #pragma unroll
    for (int mi = 0; mi < 4; ++mi) {
      int r = (mi << 4) + cc;
      kf[mi] = *(const bf16x8*)(sm + (r << 7) + (((ks << 6) + (g << 4)) ^ ((r & 7) << 4)));
    }
    #pragma unroll
    for (int nj = 0; nj < 4; ++nj) {
      int r = (nj << 4) + cc;
      qf[nj] = *(const bf16x8*)(sm + 8192 + (r << 7) + (((ks << 6) + (g << 4)) ^ ((r & 7) << 4)));
    }
    #pragma unroll
    for (int mi = 0; mi < 4; ++mi)
      #pragma unroll
      for (int nj = 0; nj < 4; ++nj)
        sacc[mi][nj] = __builtin_amdgcn_mfma_f32_16x16x32_bf16(kf[mi], qf[nj], sacc[mi][nj], 0, 0, 0);
  }
  __syncthreads();

  int r9m[4][4];
  #pragma unroll
  for (int mi = 0; mi < 4; ++mi)
    #pragma unroll
    for (int rr = 0; rr < 4; ++rr) {
      int m = (mi << 4) + (g << 2) + rr; if (m > 48) m = 48;
      int im = div7u(m), jm = m - im * 7;
      int sh = wh * 7 + im, sw = wwi * 7 + jm;
      r9m[mi][rr] = ((sh < 21) ? 0 : (sh < 25 ? 1 : 2)) * 3 + ((sw < 21) ? 0 : (sw < 25 ? 1 : 2));
    }

  #pragma unroll
  for (int nj = 0; nj < 4; ++nj) {
    int n = (nj << 4) + cc;
    int ncl = n > 48 ? 48 : n;
    int in_ = div7u(ncl), jn = ncl - in_ * 7;
    int shn = wh * 7 + in_, swn = wwi * 7 + jn;
    int r9n = ((shn < 21) ? 0 : (shn < 25 ? 1 : 2)) * 3 + ((swn < 21) ? 0 : (swn < 25 ? 1 : 2));
    float mx = -1e30f;
    #pragma unroll
    for (int mi = 0; mi < 4; ++mi) {
      f32x4 bia = *(const f32x4*)(be + (((h << 6) + n) << 6) + (mi << 4) + (g << 2));
      #pragma unroll
      for (int rr = 0; rr < 4; ++rr) {
        int m = (mi << 4) + (g << 2) + rr;
        float t = (m < 49)
            ? sacc[mi][nj][rr] * 0.125f + bia[rr] + ((r9m[mi][rr] == r9n) ? 0.f : -100.f)
            : -1e30f;
        sacc[mi][nj][rr] = t;
        mx = fmaxf(mx, t);
      }
    }
    mx = fmaxf(mx, __shfl_xor(mx, 16, 64));
    mx = fmaxf(mx, __shfl_xor(mx, 32, 64));
    float sum = 0.f;
    #pragma unroll
    for (int mi = 0; mi < 4; ++mi)
      #pragma unroll
      for (int rr = 0; rr < 4; ++rr) {
        float e = __expf(sacc[mi][nj][rr] - mx);
        sacc[mi][nj][rr] = e;
        sum += e;
      }
    sum += __shfl_xor(sum, 16, 64);
    sum += __shfl_xor(sum, 32, 64);
    float inv = __builtin_amdgcn_rcpf(sum);
    #pragma unroll
    for (int mi = 0; mi < 4; ++mi) {
      bf16x4 pk = {(__bf16)(sacc[mi][nj][0] * inv), (__bf16)(sacc[mi][nj][1] * inv),
                   (__bf16)(sacc[mi][nj][2] * inv), (__bf16)(sacc[mi][nj][3] * inv)};
      *(bf16x4*)(sm + 8192 + (n << 7) + (((mi << 5) + (g << 3)) ^ ((n & 7) << 4))) = pk;
    }
  }

  {
    int ml = lane & 15, dq = lane >> 4;
    #pragma unroll
    for (int it = 0; it < 4; ++it) {
      int m = (it << 4) + ml;
      int mc_ = m > 48 ? 48 : m;
      int im = div7u(mc_), jm = mc_ - im * 7;
      int sh = wh * 7 + im + 3; if (sh >= 28) sh -= 28;
      int sw = wwi * 7 + jm + 3; if (sw >= 28) sw -= 28;
      const __bf16* gv = qkv + (size_t)(b * 784 + sh * 28 + sw) * 1152 + 768 + h * 64;
      #pragma unroll
      for (int hd = 0; hd < 2; ++hd) {
        int dbase = (hd << 5) + (dq << 3);
        bf16x8 v = *(const bf16x8*)(gv + dbase);
        #pragma unroll
        for (int j = 0; j < 8; ++j) {
          int d = dbase + j;
          *(__bf16*)(sm + (d << 7) + ((((m >> 3) ^ (d & 7)) << 4) + ((m & 7) << 1))) = v[j];
        }
      }
    }
  }
  __syncthreads();

  f32x4 oacc[4][4] = {};
  #pragma unroll
  for (int ks = 0; ks < 2; ++ks) {
    bf16x8 pf[4], vf[4];
    #pragma unroll
    for (int ni = 0; ni < 4; ++ni) {
      int n = (ni << 4) + cc;
      pf[ni] = *(const bf16x8*)(sm + 8192 + (n << 7) + (((ks << 6) + (g << 4)) ^ ((n & 7) << 4)));
    }
    #pragma unroll
    for (int dj = 0; dj < 4; ++dj) {
      int d = (dj << 4) + cc;
      vf[dj] = *(const bf16x8*)(sm + (d << 7) + ((((ks << 2) + g) ^ (d & 7)) << 4));
    }
    #pragma unroll
    for (int ni = 0; ni < 4; ++ni)
      #pragma unroll
      for (int dj = 0; dj < 4; ++dj)
        oacc[ni][dj] = __builtin_amdgcn_mfma_f32_16x16x32_bf16(pf[ni], vf[dj], oacc[ni][dj], 0, 0, 0);
  }

  #pragma unroll
  for (int ni = 0; ni < 4; ++ni)
    #pragma unroll
    for (int rr = 0; rr < 4; ++rr) {
      int n = (ni << 4) + (g << 2) + rr;
      if (n < 49) {
        int im = div7u(n), jn = n - im * 7;
        int sh = wh * 7 + im + 3; if (sh >= 28) sh -= 28;
        int sw = wwi * 7 + jn + 3; if (sw >= 28) sw -= 28;
        __bf16* op = outt + (size_t)(b * 784 + sh * 28 + sw) * 384 + h * 64;
        #pragma unroll
        for (int dj = 0; dj < 4; ++dj)
          op[(dj << 4) + cc] = (__bf16)oacc[ni][dj][rr];
      }
    }
}

// ---------------- host launcher ----------------
extern "C" void kernel_launch(void* const* d_in, const int* in_sizes, int n_in,
                              void* d_out, int out_size, void* d_ws, size_t ws_size,
                              hipStream_t stream) {
  (void)in_sizes; (void)n_in; (void)out_size; (void)ws_size;
  const float* x     = (const float*)d_in[0];
  const float* n1w   = (const float*)d_in[1];
  const float* n1b   = (const float*)d_in[2];
  const float* qkvw  = (const float*)d_in[3];
  const float* tbl   = (const float*)d_in[4];
  const float* projw = (const float*)d_in[5];
  const float* n2w   = (const float*)d_in[6];
  const float* n2b   = (const float*)d_in[7];
  const float* w1    = (const float*)d_in[8];
  const float* w3    = (const float*)d_in[9];
  float* out = (float*)d_out;

  char* ws = (char*)d_ws;
  __bf16* bufA = (__bf16*)ws;                               // 38,535,168 B
  __bf16* bufB = (__bf16*)(ws + 38535168);                  // 115,605,504 B
  float*  be   = (float*)(ws + 154140672);                  // 98,304 B
  __bf16* wq   = (__bf16*)(ws + 154238976);
  __bf16* wp   = wq + 442368;
  __bf16* wm1  = wp + 147456;
  __bf16* wm3  = wm1 + 589824;

  cvt_all_kernel<<<6912, 256, 0, stream>>>(qkvw, projw, w1, w3, wq, wp, wm1, wm3);
  bias_expand_kernel<<<96, 256, 0, stream>>>(tbl, be);

  // LN1 -> xn_t (bufA)
  ln_t_kernel<<<784, 256, 0, stream>>>(x, n1w, n1b, bufA);
  // qkv: [1152x384] @ xn_t -> qkv_t (bufB, token-major)
  gemm_bt<0><<<392 * 9, 256, 0, stream>>>(wq, 384, bufA, 384, 384, 9, bufB, 1152, 0,
                                          nullptr, nullptr, 0);
  // attention -> attn_out_t (bufA)
  attn_kernel<<<1536, 256, 0, stream>>>(bufB, be, bufA);
  // proj + residual(x) -> d_out (fp32 channel-major)
  gemm_bt<2><<<392 * 3, 256, 0, stream>>>(wp, 384, bufA, 384, 384, 3, nullptr, 0, 0,
                                          out, x, 0);
  // LN2 -> xn2_t (bufA)
  ln_t_kernel<<<784, 256, 0, stream>>>(out, n2w, n2b, bufA);
  // MLP, token-split halves: full HID=1536 per half; h-half [25088][1536] in bufB
  for (int hh = 0; hh < 2; ++hh) {
    const int toff = hh * 25088;
    gemm_bt<1><<<196 * 12, 256, 0, stream>>>(wm1, 384, bufA + (size_t)toff * 384, 384, 384, 12,
                                             bufB, 1536, 0, nullptr, nullptr, 0);
    gemm_bt<2><<<196 * 3, 256, 0, stream>>>(wm3, 1536, bufB, 1536, 1536, 3,
                                            nullptr, 0, 0, out, out, toff);
  }
}

// Round 11
// 392.486 us; speedup vs baseline: 1.0986x; 1.0221x over previous
//
#include <hip/hip_runtime.h>
#include <hip/hip_bf16.h>

// Swin block on MI355X. Round 11: round-10 with the fp8 cvt builtins fixed —
// hi/word-sel operands must be compile-time constants (templated helpers).

typedef __bf16 bf16x8 __attribute__((ext_vector_type(8)));
typedef __bf16 bf16x4 __attribute__((ext_vector_type(4)));
typedef float  f32x4  __attribute__((ext_vector_type(4)));
typedef float  f32x2  __attribute__((ext_vector_type(2)));
typedef int    i32x4  __attribute__((ext_vector_type(4)));
typedef int    i32x2  __attribute__((ext_vector_type(2)));

#define GAS __attribute__((address_space(1)))
#define LAS __attribute__((address_space(3)))

#if __has_builtin(__builtin_amdgcn_cvt_pk_f32_fp8) && __has_builtin(__builtin_amdgcn_cvt_pk_fp8_f32)
#define HAS_HW_FP8 1
#else
#define HAS_HW_FP8 0
#endif

__device__ __forceinline__ int div7u(int m) { return (m * 37) >> 8; }  // valid m<56

#if !HAS_HW_FP8
__device__ __forceinline__ float fp8_dec1(unsigned u) {
  unsigned s = (u >> 7) & 1, e = (u >> 3) & 15, m = u & 7;
  float nrm = __uint_as_float((s << 31) | ((e + 120) << 23) | (m << 20));
  float sub = (s ? -1.f : 1.f) * (float)m * 0.001953125f;
  return e ? nrm : sub;
}
__device__ __forceinline__ unsigned fp8_enc1(float f) {
  f = fminf(fmaxf(f, -448.f), 448.f);
  unsigned u = __float_as_uint(f);
  unsigned s = u >> 31;
  int e8 = (int)((u >> 23) & 255) - 120;
  unsigned m32 = u & 0x7fffff;
  if (e8 <= 0) return s << 7;                       // FTZ (error negligible for h)
  unsigned m = m32 >> 20;
  unsigned rem = m32 & 0xfffff;
  m += (rem > 0x80000u) || (rem == 0x80000u && (m & 1));
  if (m == 8) { m = 0; ++e8; }
  if (e8 > 15 || (e8 == 15 && m == 7)) { e8 = 15; m = 6; }
  return (s << 7) | ((unsigned)e8 << 3) | m;
}
#endif

template <bool HI>
__device__ __forceinline__ f32x2 fp8_cvt2(int w) {
#if HAS_HW_FP8
  return __builtin_amdgcn_cvt_pk_f32_fp8(w, HI);
#else
  unsigned b0 = (w >> (HI ? 16 : 0)) & 255, b1 = (w >> (HI ? 24 : 8)) & 255;
  return (f32x2){fp8_dec1(b0), fp8_dec1(b1)};
#endif
}
template <bool HI>
__device__ __forceinline__ int fp8_pk2(float a, float b, int old) {
#if HAS_HW_FP8
  return __builtin_amdgcn_cvt_pk_fp8_f32(a, b, old, HI);
#else
  unsigned v = fp8_enc1(a) | (fp8_enc1(b) << 8);
  return HI ? (int)(((unsigned)old & 0xffffu) | (v << 16))
            : (int)(((unsigned)old & 0xffff0000u) | v);
#endif
}
__device__ __forceinline__ i32x4 fp8x8_to_bf16x8(i32x2 v) {
  f32x2 a = fp8_cvt2<false>(v[0]), b = fp8_cvt2<true>(v[0]);
  f32x2 c = fp8_cvt2<false>(v[1]), d = fp8_cvt2<true>(v[1]);
  bf16x8 r = {(__bf16)a[0], (__bf16)a[1], (__bf16)b[0], (__bf16)b[1],
              (__bf16)c[0], (__bf16)c[1], (__bf16)d[0], (__bf16)d[1]};
  return __builtin_bit_cast(i32x4, r);
}

// fast GELU: tanh form, |err| <= ~3e-4 (negligible vs bf16 h + 0.11 threshold)
__device__ __forceinline__ float gelu_f(float v) {
  float u = v * __builtin_fmaf(0.0356774f, v * v, 0.79788456f);
  float e = __expf(2.f * u);
  float t = 1.f - 2.f * __builtin_amdgcn_rcpf(e + 1.f);
  return 0.5f * v * (1.f + t);
}

// ---------------- weights fp32->bf16 + bias expand, one launch ----------------
__global__ __launch_bounds__(256) void cvt_all_kernel(const float* __restrict__ s0,
                                                      const float* __restrict__ s1,
                                                      const float* __restrict__ s2,
                                                      const float* __restrict__ s3,
                                                      __bf16* __restrict__ d0,
                                                      __bf16* __restrict__ d1,
                                                      __bf16* __restrict__ d2,
                                                      __bf16* __restrict__ d3,
                                                      const float* __restrict__ tbl,
                                                      float* __restrict__ be) {
  int i = blockIdx.x * 256 + threadIdx.x;
  if (i < 442368) { d0[i] = (__bf16)s0[i]; return; }
  i -= 442368;
  if (i < 147456) { d1[i] = (__bf16)s1[i]; return; }
  i -= 147456;
  if (i < 589824) { d2[i] = (__bf16)s2[i]; return; }
  i -= 589824;
  if (i < 589824) { d3[i] = (__bf16)s3[i]; return; }
  i -= 589824;
  if (i < 6 * 64 * 64) {
    int m = i & 63, n = (i >> 6) & 63, h = i >> 12;
    float v = 0.f;
    if (m < 49 && n < 49) {
      int in_ = div7u(n), jn = n - in_ * 7;
      int im  = div7u(m), jm = m - im * 7;
      v = tbl[((in_ - im + 6) * 13 + (jn - jm + 6)) * 6 + h];
    }
    be[i] = v;
  }
}

// ---------------- LayerNorm(channel) + transpose to token-major bf16 ----------------
__global__ __launch_bounds__(256) void ln_t_kernel(const float* __restrict__ x,
                                                   const float* __restrict__ gw,
                                                   const float* __restrict__ gb,
                                                   __bf16* __restrict__ out) {
  __shared__ f32x4 ps[16][16], ps2[16][16];        // [sub][gq]
  __shared__ __align__(16) __bf16 tile[64][198];
  const int tid = threadIdx.x;
  const int lane = tid & 63, w = tid >> 6;
  const int gq = lane & 15;
  const int sub = (w << 2) + (lane >> 4);
  const int tok0 = blockIdx.x << 6;
  const int tokg4 = tok0 + (gq << 2);
  const unsigned b = (unsigned)tokg4 / 784u;
  const unsigned p = (unsigned)tokg4 - b * 784u;
  const float* xp = x + (size_t)b * 301056u + p;

  f32x4 vals[24];
  f32x4 s4 = {0.f, 0.f, 0.f, 0.f}, s24 = {0.f, 0.f, 0.f, 0.f};
  #pragma unroll
  for (int half = 0; half < 2; ++half)
    #pragma unroll
    for (int k = 0; k < 12; ++k) {
      int c = half * 192 + sub * 12 + k;
      f32x4 v = *(const f32x4*)(xp + (size_t)c * 784u);
      vals[half * 12 + k] = v;
      s4 += v;
      s24 += v * v;
    }
  ps[sub][gq] = s4;
  ps2[sub][gq] = s24;
  __syncthreads();
  f32x4 S = {0.f, 0.f, 0.f, 0.f}, S2 = {0.f, 0.f, 0.f, 0.f};
  #pragma unroll
  for (int i = 0; i < 16; ++i) { S += ps[i][gq]; S2 += ps2[i][gq]; }
  f32x4 mean = S * (1.f / 384.f);
  f32x4 var = (S2 - S * mean) * (1.f / 383.f);     // unbiased (ddof=1)
  f32x4 rstd;
  #pragma unroll
  for (int j = 0; j < 4; ++j) rstd[j] = rsqrtf(var[j] + 1e-5f);

  #pragma unroll
  for (int half = 0; half < 2; ++half) {
    if (half) __syncthreads();
    #pragma unroll
    for (int k = 0; k < 12; ++k) {
      int c = half * 192 + sub * 12 + k;
      float wgt = gw[c], bia = gb[c];
      f32x4 v = (vals[half * 12 + k] - mean) * rstd * wgt + bia;
      #pragma unroll
      for (int j = 0; j < 4; ++j)
        tile[(gq << 2) + j][sub * 12 + k] = (__bf16)v[j];
    }
    __syncthreads();
    #pragma unroll
    for (int it = 0; it < 6; ++it) {
      int idx = (it << 8) + tid;
      int row = idx / 24, colc = idx - row * 24;
      bf16x8 vv = *(const bf16x8*)(&tile[row][colc << 3]);
      *(bf16x8*)(out + (size_t)(tok0 + row) * 384 + half * 192 + (colc << 3)) = vv;
    }
  }
}

// ---------------- GEMM: C[m][tok] = sum_k A[m][k] * Bt[tok][k] ----------------
// 128x128 tile, BK=64, single LDS buffer (3 blocks/CU), reg-staged prefetch.
// EPI 0: LDS-transpose -> bf16 outT[tok][ldo] @ ocol
// EPI 1: same + fast GELU; F8: emit fp8 h
// EPI 2: swapped-operand acc -> float4 resid+store fp32; F8: B-operand is fp8
template <int EPI, int F8>
__global__ __launch_bounds__(256, 3) void gemm_bt(const __bf16* __restrict__ A, int lda,
                                                  const void* __restrict__ BtV, int ldb,
                                                  int K, int My,
                                                  void* __restrict__ outT, int ldo, int ocol,
                                                  float* __restrict__ outR,
                                                  const float* __restrict__ resid,
                                                  int tok_off) {
  constexpr bool B8 = (F8 && EPI == 2);
  constexpr int esz = B8 ? 1 : 2;
  __shared__ __align__(16) char smem[33792];
  const int tid = threadIdx.x;
  const int lane = tid & 63;
  const int w = tid >> 6;
  const int wr = w >> 1, wc = w & 1;
  const int c = lane & 15, g = lane >> 4;

  const int nwg = gridDim.x;
  const int orig = blockIdx.x;
  const int q = nwg >> 3, r = nwg & 7;
  const int xcd = orig & 7, ii = orig >> 3;
  const int wgid = (xcd < r ? xcd * (q + 1) : r * (q + 1) + (xcd - r) * q) + ii;
  const int bx = wgid / My;
  const int by = wgid - bx * My;
  const int m0 = by << 7;
  const int n0 = bx << 7;

  const __bf16* ap[4];
  const unsigned char* bp[4];
  #pragma unroll
  for (int i = 0; i < 4; ++i) {
    int s = (i << 8) + tid;
    int row = s >> 3;
    int kk = ((s ^ row) & 7) << 3;
    ap[i] = A + (size_t)(m0 + row) * lda + kk;
    bp[i] = (const unsigned char*)BtV + ((size_t)(n0 + row) * ldb + kk) * esz;
  }

  i32x4 sA0, sA1, sA2, sA3;
  i32x4 sB0, sB1, sB2, sB3;        // bf16 path
  i32x2 t0, t1, t2, t3;            // fp8 path
  auto issue = [&](int k0) {
    sA0 = *(const i32x4*)(ap[0] + k0);
    sA1 = *(const i32x4*)(ap[1] + k0);
    sA2 = *(const i32x4*)(ap[2] + k0);
    sA3 = *(const i32x4*)(ap[3] + k0);
    if constexpr (B8) {
      t0 = *(const i32x2*)(bp[0] + k0);
      t1 = *(const i32x2*)(bp[1] + k0);
      t2 = *(const i32x2*)(bp[2] + k0);
      t3 = *(const i32x2*)(bp[3] + k0);
    } else {
      sB0 = *(const i32x4*)(bp[0] + k0 * 2);
      sB1 = *(const i32x4*)(bp[1] + k0 * 2);
      sB2 = *(const i32x4*)(bp[2] + k0 * 2);
      sB3 = *(const i32x4*)(bp[3] + k0 * 2);
    }
  };
  auto write_lds = [&]() {
    *(i32x4*)(smem +         (((0 << 8) + tid) << 4)) = sA0;
    *(i32x4*)(smem +         (((1 << 8) + tid) << 4)) = sA1;
    *(i32x4*)(smem +         (((2 << 8) + tid) << 4)) = sA2;
    *(i32x4*)(smem +         (((3 << 8) + tid) << 4)) = sA3;
    if constexpr (B8) {
      *(i32x4*)(smem + 16384 + (((0 << 8) + tid) << 4)) = fp8x8_to_bf16x8(t0);
      *(i32x4*)(smem + 16384 + (((1 << 8) + tid) << 4)) = fp8x8_to_bf16x8(t1);
      *(i32x4*)(smem + 16384 + (((2 << 8) + tid) << 4)) = fp8x8_to_bf16x8(t2);
      *(i32x4*)(smem + 16384 + (((3 << 8) + tid) << 4)) = fp8x8_to_bf16x8(t3);
    } else {
      *(i32x4*)(smem + 16384 + (((0 << 8) + tid) << 4)) = sB0;
      *(i32x4*)(smem + 16384 + (((1 << 8) + tid) << 4)) = sB1;
      *(i32x4*)(smem + 16384 + (((2 << 8) + tid) << 4)) = sB2;
      *(i32x4*)(smem + 16384 + (((3 << 8) + tid) << 4)) = sB3;
    }
  };

  f32x4 acc[4][4] = {};
  const int nt = K >> 6;

  issue(0);
  write_lds();
  asm volatile("s_waitcnt lgkmcnt(0)" ::: "memory");
  __builtin_amdgcn_s_barrier();
  __builtin_amdgcn_sched_barrier(0);

  for (int t = 0; t < nt; ++t) {
    if (t + 1 < nt) issue((t + 1) << 6);
    const char* smA = smem;
    const char* smB = smem + 16384;
    #pragma unroll
    for (int ks = 0; ks < 2; ++ks) {
      bf16x8 af[4], bfv[4];
      #pragma unroll
      for (int mi = 0; mi < 4; ++mi) {
        int r2 = (wr << 6) + (mi << 4) + c;
        af[mi] = *(const bf16x8*)(smA + (r2 << 7) + (((ks << 6) + (g << 4)) ^ ((r2 & 7) << 4)));
      }
      #pragma unroll
      for (int nj = 0; nj < 4; ++nj) {
        int r2 = (wc << 6) + (nj << 4) + c;
        bfv[nj] = *(const bf16x8*)(smB + (r2 << 7) + (((ks << 6) + (g << 4)) ^ ((r2 & 7) << 4)));
      }
      #pragma unroll
      for (int mi = 0; mi < 4; ++mi)
        #pragma unroll
        for (int nj = 0; nj < 4; ++nj) {
          if constexpr (EPI == 2)  // swapped: C rows = tokens
            acc[mi][nj] = __builtin_amdgcn_mfma_f32_16x16x32_bf16(bfv[nj], af[mi], acc[mi][nj], 0, 0, 0);
          else
            acc[mi][nj] = __builtin_amdgcn_mfma_f32_16x16x32_bf16(af[mi], bfv[nj], acc[mi][nj], 0, 0, 0);
        }
    }
    __builtin_amdgcn_s_barrier();
    if (t + 1 < nt) {
      write_lds();
      asm volatile("s_waitcnt lgkmcnt(0)" ::: "memory");
    }
    __builtin_amdgcn_s_barrier();
    __builtin_amdgcn_sched_barrier(0);
  }

  if constexpr (EPI <= 1) {
    #pragma unroll
    for (int mi = 0; mi < 4; ++mi)
      #pragma unroll
      for (int nj = 0; nj < 4; ++nj) {
        f32x4 v = acc[mi][nj];
        if constexpr (EPI == 1) {
          #pragma unroll
          for (int r2 = 0; r2 < 4; ++r2) v[r2] = gelu_f(v[r2]);
        }
        bf16x4 pk = {(__bf16)v[0], (__bf16)v[1], (__bf16)v[2], (__bf16)v[3]};
        int nl = (wc << 6) + (nj << 4) + c;
        int ml = (wr << 6) + (mi << 4) + (g << 2);
        *(bf16x4*)(smem + nl * 264 + ml * 2) = pk;
      }
    __syncthreads();
    #pragma unroll
    for (int it = 0; it < 8; ++it) {
      int id = (it << 8) + tid;
      int n = id >> 4, mc = id & 15;
      bf16x8 v = *(const bf16x8*)(smem + n * 264 + (mc << 4));
      if constexpr (F8) {
        int w0 = 0, w1 = 0;
        w0 = fp8_pk2<false>((float)v[0], (float)v[1], w0);
        w0 = fp8_pk2<true>((float)v[2], (float)v[3], w0);
        w1 = fp8_pk2<false>((float)v[4], (float)v[5], w1);
        w1 = fp8_pk2<true>((float)v[6], (float)v[7], w1);
        *(i32x2*)((unsigned char*)outT + (size_t)(n0 + n) * ldo + (ocol + m0 + (mc << 3))) =
            (i32x2){w0, w1};
      } else {
        *(bf16x8*)((__bf16*)outT + (size_t)(n0 + n) * ldo + (ocol + m0 + (mc << 3))) = v;
      }
    }
  } else {
    #pragma unroll
    for (int nj = 0; nj < 4; ++nj) {
      int tokb = tok_off + n0 + (wc << 6) + (nj << 4) + (g << 2);
      unsigned bb = (unsigned)tokb / 784u;
      unsigned pp = (unsigned)tokb - bb * 784u;
      size_t base2 = (size_t)bb * (384u * 784u) + pp;
      #pragma unroll
      for (int mi = 0; mi < 4; ++mi) {
        int o = m0 + (wr << 6) + (mi << 4) + c;
        size_t a2 = base2 + (size_t)o * 784u;
        f32x4 rv = *(const f32x4*)(resid + a2);
        f32x4 v = acc[mi][nj] + rv;
        *(f32x4*)(outR + a2) = v;
      }
    }
  }
}

// ---------------- windowed attention: 1 wave per (window, head) ----------------
__global__ __launch_bounds__(256, 2) void attn_kernel(const __bf16* __restrict__ qkv,
                                                      const float* __restrict__ be,
                                                      __bf16* __restrict__ outt) {
  __shared__ __align__(16) char smem_all[4][16384];
  const int tid = threadIdx.x;
  const int lane = tid & 63;
  const int w = tid >> 6;
  char* sm = (char*)smem_all[w];
  const int pair = blockIdx.x * 4 + w;               // 6144 pairs
  const int h = pair % 6;
  const int wg = pair / 6;
  const int b = wg >> 4;
  const int wi = wg & 15;
  const int wh = wi >> 2, wwi = wi & 3;
  const int cc = lane & 15, g = lane >> 4;

  {
    int rsub = lane >> 3;
    int slot = lane & 7;
    int dc = (slot ^ rsub) << 3;
    #pragma unroll
    for (int i = 0; i < 8; ++i) {
      int r = i * 8 + rsub;
      int m = r < 49 ? r : 48;
      int im = div7u(m), jm = m - im * 7;
      int sh = wh * 7 + im + 3; if (sh >= 28) sh -= 28;
      int sw = wwi * 7 + jm + 3; if (sw >= 28) sw -= 28;
      size_t trow = (size_t)(b * 784 + sh * 28 + sw) * 1152;
      __builtin_amdgcn_global_load_lds((const GAS void*)(qkv + trow + 384 + h * 64 + dc),
                                       (LAS void*)(sm + i * 1024), 16, 0, 0);
      __builtin_amdgcn_global_load_lds((const GAS void*)(qkv + trow + h * 64 + dc),
                                       (LAS void*)(sm + 8192 + i * 1024), 16, 0, 0);
    }
  }
  asm volatile("s_waitcnt vmcnt(0)" ::: "memory");
  __syncthreads();

  f32x4 sacc[4][4] = {};
  #pragma unroll
  for (int ks = 0; ks < 2; ++ks) {
    bf16x8 kf[4], qf[4];
    #pragma unroll
    for (int mi = 0; mi < 4; ++mi) {
      int r = (mi << 4) + cc;
      kf[mi] = *(const bf16x8*)(sm + (r << 7) + (((ks << 6) + (g << 4)) ^ ((r & 7) << 4)));
    }
    #pragma unroll
    for (int nj = 0; nj < 4; ++nj) {
      int r = (nj << 4) + cc;
      qf[nj] = *(const bf16x8*)(sm + 8192 + (r << 7) + (((ks << 6) + (g << 4)) ^ ((r & 7) << 4)));
    }
    #pragma unroll
    for (int mi = 0; mi < 4; ++mi)
      #pragma unroll
      for (int nj = 0; nj < 4; ++nj)
        sacc[mi][nj] = __builtin_amdgcn_mfma_f32_16x16x32_bf16(kf[mi], qf[nj], sacc[mi][nj], 0, 0, 0);
  }
  __syncthreads();

  int r9m[4][4];
  #pragma unroll
  for (int mi = 0; mi < 4; ++mi)
    #pragma unroll
    for (int rr = 0; rr < 4; ++rr) {
      int m = (mi << 4) + (g << 2) + rr; if (m > 48) m = 48;
      int im = div7u(m), jm = m - im * 7;
      int sh = wh * 7 + im, sw = wwi * 7 + jm;
      r9m[mi][rr] = ((sh < 21) ? 0 : (sh < 25 ? 1 : 2)) * 3 + ((sw < 21) ? 0 : (sw < 25 ? 1 : 2));
    }

  #pragma unroll
  for (int nj = 0; nj < 4; ++nj) {
    int n = (nj << 4) + cc;
    int ncl = n > 48 ? 48 : n;
    int in_ = div7u(ncl), jn = ncl - in_ * 7;
    int shn = wh * 7 + in_, swn = wwi * 7 + jn;
    int r9n = ((shn < 21) ? 0 : (shn < 25 ? 1 : 2)) * 3 + ((swn < 21) ? 0 : (swn < 25 ? 1 : 2));
    float mx = -1e30f;
    #pragma unroll
    for (int mi = 0; mi < 4; ++mi) {
      f32x4 bia = *(const f32x4*)(be + (((h << 6) + n) << 6) + (mi << 4) + (g << 2));
      #pragma unroll
      for (int rr = 0; rr < 4; ++rr) {
        int m = (mi << 4) + (g << 2) + rr;
        float t = (m < 49)
            ? sacc[mi][nj][rr] * 0.125f + bia[rr] + ((r9m[mi][rr] == r9n) ? 0.f : -100.f)
            : -1e30f;
        sacc[mi][nj][rr] = t;
        mx = fmaxf(mx, t);
      }
    }
    mx = fmaxf(mx, __shfl_xor(mx, 16, 64));
    mx = fmaxf(mx, __shfl_xor(mx, 32, 64));
    float sum = 0.f;
    #pragma unroll
    for (int mi = 0; mi < 4; ++mi)
      #pragma unroll
      for (int rr = 0; rr < 4; ++rr) {
        float e = __expf(sacc[mi][nj][rr] - mx);
        sacc[mi][nj][rr] = e;
        sum += e;
      }
    sum += __shfl_xor(sum, 16, 64);
    sum += __shfl_xor(sum, 32, 64);
    float inv = __builtin_amdgcn_rcpf(sum);
    #pragma unroll
    for (int mi = 0; mi < 4; ++mi) {
      bf16x4 pk = {(__bf16)(sacc[mi][nj][0] * inv), (__bf16)(sacc[mi][nj][1] * inv),
                   (__bf16)(sacc[mi][nj][2] * inv), (__bf16)(sacc[mi][nj][3] * inv)};
      *(bf16x4*)(sm + 8192 + (n << 7) + (((mi << 5) + (g << 3)) ^ ((n & 7) << 4))) = pk;
    }
  }

  {
    int ml = lane & 15, dq = lane >> 4;
    #pragma unroll
    for (int it = 0; it < 4; ++it) {
      int m = (it << 4) + ml;
      int mc_ = m > 48 ? 48 : m;
      int im = div7u(mc_), jm = mc_ - im * 7;
      int sh = wh * 7 + im + 3; if (sh >= 28) sh -= 28;
      int sw = wwi * 7 + jm + 3; if (sw >= 28) sw -= 28;
      const __bf16* gv = qkv + (size_t)(b * 784 + sh * 28 + sw) * 1152 + 768 + h * 64;
      #pragma unroll
      for (int hd = 0; hd < 2; ++hd) {
        int dbase = (hd << 5) + (dq << 3);
        bf16x8 v = *(const bf16x8*)(gv + dbase);
        #pragma unroll
        for (int j = 0; j < 8; ++j) {
          int d = dbase + j;
          *(__bf16*)(sm + (d << 7) + ((((m >> 3) ^ (d & 7)) << 4) + ((m & 7) << 1))) = v[j];
        }
      }
    }
  }
  __syncthreads();

  f32x4 oacc[4][4] = {};
  #pragma unroll
  for (int ks = 0; ks < 2; ++ks) {
    bf16x8 pf[4], vf[4];
    #pragma unroll
    for (int ni = 0; ni < 4; ++ni) {
      int n = (ni << 4) + cc;
      pf[ni] = *(const bf16x8*)(sm + 8192 + (n << 7) + (((ks << 6) + (g << 4)) ^ ((n & 7) << 4)));
    }
    #pragma unroll
    for (int dj = 0; dj < 4; ++dj) {
      int d = (dj << 4) + cc;
      vf[dj] = *(const bf16x8*)(sm + (d << 7) + ((((ks << 2) + g) ^ (d & 7)) << 4));
    }
    #pragma unroll
    for (int ni = 0; ni < 4; ++ni)
      #pragma unroll
      for (int dj = 0; dj < 4; ++dj)
        oacc[ni][dj] = __builtin_amdgcn_mfma_f32_16x16x32_bf16(pf[ni], vf[dj], oacc[ni][dj], 0, 0, 0);
  }

  #pragma unroll
  for (int ni = 0; ni < 4; ++ni)
    #pragma unroll
    for (int rr = 0; rr < 4; ++rr) {
      int n = (ni << 4) + (g << 2) + rr;
      if (n < 49) {
        int im = div7u(n), jn = n - im * 7;
        int sh = wh * 7 + im + 3; if (sh >= 28) sh -= 28;
        int sw = wwi * 7 + jn + 3; if (sw >= 28) sw -= 28;
        __bf16* op = outt + (size_t)(b * 784 + sh * 28 + sw) * 384 + h * 64;
        #pragma unroll
        for (int dj = 0; dj < 4; ++dj)
          op[(dj << 4) + cc] = (__bf16)oacc[ni][dj][rr];
      }
    }
}

// ---------------- host launcher ----------------
extern "C" void kernel_launch(void* const* d_in, const int* in_sizes, int n_in,
                              void* d_out, int out_size, void* d_ws, size_t ws_size,
                              hipStream_t stream) {
  (void)in_sizes; (void)n_in; (void)out_size; (void)ws_size;
  const float* x     = (const float*)d_in[0];
  const float* n1w   = (const float*)d_in[1];
  const float* n1b   = (const float*)d_in[2];
  const float* qkvw  = (const float*)d_in[3];
  const float* tbl   = (const float*)d_in[4];
  const float* projw = (const float*)d_in[5];
  const float* n2w   = (const float*)d_in[6];
  const float* n2b   = (const float*)d_in[7];
  const float* w1    = (const float*)d_in[8];
  const float* w3    = (const float*)d_in[9];
  float* out = (float*)d_out;

  char* ws = (char*)d_ws;
  __bf16* bufA = (__bf16*)ws;                               // 38,535,168 B
  __bf16* bufB = (__bf16*)(ws + 38535168);                  // 115,605,504 B
  float*  be   = (float*)(ws + 154140672);                  // 98,304 B
  __bf16* wq   = (__bf16*)(ws + 154238976);
  __bf16* wp   = wq + 442368;
  __bf16* wm1  = wp + 147456;
  __bf16* wm3  = wm1 + 589824;

  // 442368+147456+589824+589824+24576 = 1,794,048 threads
  cvt_all_kernel<<<7008, 256, 0, stream>>>(qkvw, projw, w1, w3, wq, wp, wm1, wm3, tbl, be);

  // LN1 -> xn_t (bufA)
  ln_t_kernel<<<784, 256, 0, stream>>>(x, n1w, n1b, bufA);
  // qkv: [1152x384] @ xn_t -> qkv_t (bufB, token-major bf16)
  gemm_bt<0, 0><<<392 * 9, 256, 0, stream>>>(wq, 384, bufA, 384, 384, 9,
                                             bufB, 1152, 0, nullptr, nullptr, 0);
  // attention -> attn_out_t (bufA)
  attn_kernel<<<1536, 256, 0, stream>>>(bufB, be, bufA);
  // proj + residual(x) -> d_out (fp32 channel-major)
  gemm_bt<2, 0><<<392 * 3, 256, 0, stream>>>(wp, 384, bufA, 384, 384, 3,
                                             nullptr, 0, 0, out, x, 0);
  // LN2 -> xn2_t (bufA)
  ln_t_kernel<<<784, 256, 0, stream>>>(out, n2w, n2b, bufA);
  // MLP, token-split halves; h [25088][1536] fp8 e4m3 in bufB
  unsigned char* h8 = (unsigned char*)bufB;
  for (int hh = 0; hh < 2; ++hh) {
    const int toff = hh * 25088;
    gemm_bt<1, 1><<<196 * 12, 256, 0, stream>>>(wm1, 384, bufA + (size_t)toff * 384, 384, 384, 12,
                                                (void*)h8, 1536, 0, nullptr, nullptr, 0);
    gemm_bt<2, 1><<<196 * 3, 256, 0, stream>>>(wm3, 1536, (const void*)h8, 1536, 1536, 3,
                                               nullptr, 0, 0, out, out, toff);
  }
}